// Round 1
// baseline (802.362 us; speedup 1.0000x reference)
//
#include <hip/hip_runtime.h>
#include <hip/hip_bf16.h>
#include <math.h>

// ---------------------------------------------------------------------------
// NasAutoGraphC: 2x (pre-linear -> ChebConv(K=2) + SAGEConv -> leaky -> linear)
// -> classifier -> log_softmax.  All fp32.
// Strategy this round:
//   * graph normalization (deg/dis/cnt/loop_w) computed once, shared by cells
//   * CSR-by-dst built per call (histogram + hierarchical scan + scatter)
//   * one wave-per-node aggregation produces BOTH cheb tx1 and sage mean
//   * tiled fp32 vector GEMM (BM=64, BN=128, BK=32), dual-A variant for cheb,
//     leaky-combine epilogue variant for sage, fused bias everywhere
//   * classifier + log_softmax fused, wave per node
// ---------------------------------------------------------------------------

#define BM 64
#define BK 32

__device__ __forceinline__ float leaky01(float v) {
    return v > 0.f ? v : 0.01f * v;
}

// ---- graph preprocessing ---------------------------------------------------

__global__ void init_nodes(float* __restrict__ deg, int* __restrict__ cnt,
                           float* __restrict__ loop_w, int n) {
    int i = blockIdx.x * blockDim.x + threadIdx.x;
    if (i < n) { deg[i] = 0.f; cnt[i] = 0; loop_w[i] = 1.0f; }
}

__global__ void edge_pass1(const int* __restrict__ src, const int* __restrict__ dst,
                           const float* __restrict__ ew, float* __restrict__ deg,
                           int* __restrict__ cnt, float* __restrict__ loop_w, int E) {
    int e = blockIdx.x * blockDim.x + threadIdx.x;
    if (e >= E) return;
    int s = src[e], d = dst[e];
    float w = ew[e];
    if (s == d) {
        loop_w[s] = w;                      // PyG keeps existing loop weight
    } else {
        atomicAdd(&deg[s], w);              // weighted out-degree (loops removed)
        atomicAdd(&cnt[d], 1);              // non-loop in-degree
    }
}

// single-block hierarchical exclusive scan over cnt -> offsets/cursor; also dis
__global__ void scan_kernel(const int* __restrict__ cnt, const float* __restrict__ deg,
                            int* __restrict__ offsets, int* __restrict__ cursor,
                            float* __restrict__ dis, int n) {
    __shared__ int wsum[16];
    __shared__ int carry;
    const int tid  = threadIdx.x;
    const int lane = tid & 63;
    const int wv   = tid >> 6;
    if (tid == 0) carry = 0;
    __syncthreads();
    const int nchunks = (n + 1023) >> 10;
    for (int ch = 0; ch < nchunks; ++ch) {
        int i = (ch << 10) + tid;
        int v = (i < n) ? cnt[i] : 0;
        if (i < n) {
            float d = deg[i];
            dis[i] = (d > 0.f) ? (1.0f / sqrtf(d)) : 0.f;
        }
        int incl = v;
        #pragma unroll
        for (int off = 1; off < 64; off <<= 1) {
            int t = __shfl_up(incl, off);
            if (lane >= off) incl += t;
        }
        if (lane == 63) wsum[wv] = incl;
        __syncthreads();
        if (tid < 16) {
            int s = wsum[tid];
            #pragma unroll
            for (int off = 1; off < 16; off <<= 1) {
                int u = __shfl_up(s, off);
                if (tid >= off) s += u;
            }
            wsum[tid] = s;                  // inclusive over wave totals
        }
        __syncthreads();
        int base = carry + (wv ? wsum[wv - 1] : 0);
        int excl = base + incl - v;
        if (i < n) { offsets[i] = excl; cursor[i] = excl; }
        __syncthreads();
        if (tid == 0) carry += wsum[15];
        __syncthreads();
    }
    if (tid == 0) offsets[n] = carry;
}

__global__ void edge_pass2(const int* __restrict__ src, const int* __restrict__ dst,
                           const float* __restrict__ ew, const float* __restrict__ dis,
                           int* __restrict__ cursor, int* __restrict__ slot_src,
                           float* __restrict__ slot_norm, float* __restrict__ slot_we,
                           int E) {
    int e = blockIdx.x * blockDim.x + threadIdx.x;
    if (e >= E) return;
    int s = src[e], d = dst[e];
    if (s == d) return;                     // loops contribute 0 to both aggs
    float w = ew[e];
    float nrm = -dis[s] * w * dis[d];
    int pos = atomicAdd(&cursor[d], 1);
    slot_src[pos]  = s;
    slot_norm[pos] = nrm;
    slot_we[pos]   = w;
}

// ---- aggregation: one wave per dst node; produces tx1 and sage-mean --------

__global__ __launch_bounds__(256) void aggregate_kernel(
    const float* __restrict__ xh, const int* __restrict__ offsets,
    const int* __restrict__ slot_src, const float* __restrict__ slot_norm,
    const float* __restrict__ slot_we, const float* __restrict__ loop_w,
    const int* __restrict__ cnt, float* __restrict__ tx1,
    float* __restrict__ sagg, int n)
{
    const int lane = threadIdx.x & 63;
    const int wv   = threadIdx.x >> 6;
    const int node = (blockIdx.x << 2) + wv;
    if (node >= n) return;
    const int beg = offsets[node], end = offsets[node + 1];
    const int c = lane << 1;                // 2 floats per lane = 128 dims
    float ax = 0.f, ay = 0.f, sx = 0.f, sy = 0.f;
    for (int e = beg; e < end; ++e) {
        const int   s  = slot_src[e];
        const float nr = slot_norm[e];
        const float we = slot_we[e];
        const float2 v = *(const float2*)&xh[((size_t)s << 7) + c];
        ax = fmaf(nr, v.x, ax); ay = fmaf(nr, v.y, ay);
        sx = fmaf(we, v.x, sx); sy = fmaf(we, v.y, sy);
    }
    const float2 vs = *(const float2*)&xh[((size_t)node << 7) + c];
    const float lw = loop_w[node];
    sx = fmaf(lw, vs.x, sx); sy = fmaf(lw, vs.y, sy);
    const float inv = 1.0f / (float)(cnt[node] + 1);
    *(float2*)&tx1[((size_t)node << 7) + c]  = make_float2(ax, ay);
    *(float2*)&sagg[((size_t)node << 7) + c] = make_float2(sx * inv, sy * inv);
}

// ---- tiled fp32 GEMM: out = A1@W1 (+ A2@W2) + bias; N fixed at 128 ---------
// mode 0: plain store.  mode 1: out = leaky(r) + leaky(comb)  (sage combine)

__global__ __launch_bounds__(256) void gemm_fused(
    const float* __restrict__ A1, const float* __restrict__ W1, int K1,
    const float* __restrict__ A2, const float* __restrict__ W2, int K2,
    const float* __restrict__ bias, const float* __restrict__ comb,
    float* __restrict__ out, int M, int mode)
{
    __shared__ float As[BK][72];            // A tile, TRANSPOSED: As[k][r]
    __shared__ float Ws[BK][128];           // W tile
    const int tid = threadIdx.x;
    const int tx = tid & 15;                // col group: 8 cols each
    const int ty = tid >> 4;                // row group: 4 rows each
    const int row0 = blockIdx.x * BM;

    float acc[4][8];
    #pragma unroll
    for (int i = 0; i < 4; ++i)
        #pragma unroll
        for (int j = 0; j < 8; ++j) acc[i][j] = 0.f;

    for (int part = 0; part < 2; ++part) {
        const float* A = part ? A2 : A1;
        const float* W = part ? W2 : W1;
        const int    K = part ? K2 : K1;
        if (A == nullptr) continue;
        for (int k0 = 0; k0 < K; k0 += BK) {
            // stage A (64 rows x 32 k), transposed into LDS
            #pragma unroll
            for (int q = 0; q < 2; ++q) {
                int f  = tid * 2 + q;       // 0..511 float4 slots
                int r  = f >> 3;
                int c4 = (f & 7) << 2;
                int row = row0 + r; if (row >= M) row = 0;
                float4 a = *(const float4*)&A[(size_t)row * K + k0 + c4];
                As[c4 + 0][r] = a.x; As[c4 + 1][r] = a.y;
                As[c4 + 2][r] = a.z; As[c4 + 3][r] = a.w;
            }
            // stage W (32 k x 128 cols)
            {
                int kk = tid >> 3;
                int c  = (tid & 7) << 2;
                const float* wp = &W[(size_t)(k0 + kk) * 128 + c];
                #pragma unroll
                for (int j = 0; j < 4; ++j)
                    *(float4*)&Ws[kk][c + 32 * j] = *(const float4*)&wp[32 * j];
            }
            __syncthreads();
            #pragma unroll
            for (int kk = 0; kk < BK; ++kk) {
                const float4 a  = *(const float4*)&As[kk][ty << 2];
                const float4 w0 = *(const float4*)&Ws[kk][tx << 3];
                const float4 w1 = *(const float4*)&Ws[kk][(tx << 3) + 4];
                const float av[4] = {a.x, a.y, a.z, a.w};
                const float wv8[8] = {w0.x, w0.y, w0.z, w0.w,
                                      w1.x, w1.y, w1.z, w1.w};
                #pragma unroll
                for (int i = 0; i < 4; ++i)
                    #pragma unroll
                    for (int j = 0; j < 8; ++j)
                        acc[i][j] = fmaf(av[i], wv8[j], acc[i][j]);
            }
            __syncthreads();
        }
    }

    float bv[8];
    #pragma unroll
    for (int j = 0; j < 8; ++j) bv[j] = bias[(tx << 3) + j];
    #pragma unroll
    for (int i = 0; i < 4; ++i) {
        int row = row0 + (ty << 2) + i;
        if (row >= M) continue;
        float vals[8];
        #pragma unroll
        for (int j = 0; j < 8; ++j) vals[j] = acc[i][j] + bv[j];
        if (mode == 1) {
            const float* cp = &comb[(size_t)row * 128 + (tx << 3)];
            #pragma unroll
            for (int j = 0; j < 8; ++j)
                vals[j] = leaky01(vals[j]) + leaky01(cp[j]);
        }
        float* op = &out[(size_t)row * 128 + (tx << 3)];
        *(float4*)op       = make_float4(vals[0], vals[1], vals[2], vals[3]);
        *((float4*)op + 1) = make_float4(vals[4], vals[5], vals[6], vals[7]);
    }
}

// ---- classifier + log_softmax, wave per node -------------------------------

__global__ __launch_bounds__(256) void cls_kernel(
    const float* __restrict__ x2, const float* __restrict__ w,
    const float* __restrict__ b, float* __restrict__ out, int n, int C)
{
    const int lane = threadIdx.x & 63;
    const int wv   = threadIdx.x >> 6;
    const int node = (blockIdx.x << 2) + wv;
    if (node >= n) return;
    const float* xr = &x2[(size_t)node << 7];
    float acc;
    if (lane < C) {
        float a = 0.f;
        #pragma unroll 8
        for (int k = 0; k < 128; ++k) a = fmaf(xr[k], w[k * C + lane], a);
        acc = a + b[lane];
    } else {
        acc = -INFINITY;
    }
    float m = acc;
    #pragma unroll
    for (int off = 32; off; off >>= 1) m = fmaxf(m, __shfl_xor(m, off));
    float ex = (lane < C) ? expf(acc - m) : 0.f;
    float s = ex;
    #pragma unroll
    for (int off = 32; off; off >>= 1) s += __shfl_xor(s, off);
    const float ls = logf(s);
    if (lane < C) out[(size_t)node * C + lane] = acc - m - ls;
}

// ---------------------------------------------------------------------------

extern "C" void kernel_launch(void* const* d_in, const int* in_sizes, int n_in,
                              void* d_out, int out_size, void* d_ws, size_t ws_size,
                              hipStream_t stream)
{
    const float* x        = (const float*)d_in[0];
    const int*   ei       = (const int*)d_in[1];
    const float* ew       = (const float*)d_in[2];
    const float* pre_w1   = (const float*)d_in[3];
    const float* pre_b1   = (const float*)d_in[4];
    const float* cheb_w01 = (const float*)d_in[5];
    const float* cheb_w11 = (const float*)d_in[6];
    const float* cheb_b1  = (const float*)d_in[7];
    const float* sage_w1  = (const float*)d_in[8];
    const float* sage_b1  = (const float*)d_in[9];
    const float* lin_w1   = (const float*)d_in[10];
    const float* lin_b1   = (const float*)d_in[11];
    const float* pre_w2   = (const float*)d_in[12];
    const float* pre_b2   = (const float*)d_in[13];
    const float* cheb_w02 = (const float*)d_in[14];
    const float* cheb_w12 = (const float*)d_in[15];
    const float* cheb_b2  = (const float*)d_in[16];
    const float* sage_w2  = (const float*)d_in[17];
    const float* sage_b2  = (const float*)d_in[18];
    const float* lin_w2   = (const float*)d_in[19];
    const float* lin_b2   = (const float*)d_in[20];
    const float* cls_w    = (const float*)d_in[21];
    const float* cls_b    = (const float*)d_in[22];

    const int H    = 128;
    const int F_IN = in_sizes[3] / H;       // 512
    const int N    = in_sizes[0] / F_IN;    // 40000
    const int E    = in_sizes[2];           // 640000
    const int C    = in_sizes[21] / H;      // 40
    const int* src = ei;
    const int* dst = ei + E;

    // workspace carve-up (256B aligned); total ~91 MB
    char* p = (char*)d_ws;
    auto alloc = [&](size_t bytes) -> void* {
        void* r = (void*)p;
        p += (bytes + 255) & ~(size_t)255;
        return r;
    };
    float* buf0 = (float*)alloc((size_t)N * 128 * 4);
    float* buf1 = (float*)alloc((size_t)N * 128 * 4);
    float* buf2 = (float*)alloc((size_t)N * 128 * 4);
    float* buf3 = (float*)alloc((size_t)N * 128 * 4);
    float* deg     = (float*)alloc((size_t)N * 4);
    float* dis     = (float*)alloc((size_t)N * 4);
    float* loop_w  = (float*)alloc((size_t)N * 4);
    int*   cnt     = (int*)alloc((size_t)N * 4);
    int*   offs    = (int*)alloc((size_t)(N + 1) * 4);
    int*   cursor  = (int*)alloc((size_t)N * 4);
    int*   slot_src  = (int*)alloc((size_t)E * 4);
    float* slot_nrm  = (float*)alloc((size_t)E * 4);
    float* slot_we   = (float*)alloc((size_t)E * 4);
    (void)ws_size; (void)n_in; (void)out_size;

    const int nb_n = (N + 255) / 256;
    const int nb_e = (E + 255) / 256;
    const int nb_w = (N + 3) / 4;           // wave-per-node kernels
    const int nb_g = (N + BM - 1) / BM;     // GEMM blocks

    // graph preprocessing (shared by both cells)
    init_nodes<<<nb_n, 256, 0, stream>>>(deg, cnt, loop_w, N);
    edge_pass1<<<nb_e, 256, 0, stream>>>(src, dst, ew, deg, cnt, loop_w, E);
    scan_kernel<<<1, 1024, 0, stream>>>(cnt, deg, offs, cursor, dis, N);
    edge_pass2<<<nb_e, 256, 0, stream>>>(src, dst, ew, dis, cursor,
                                         slot_src, slot_nrm, slot_we, E);

    // ---- cell 1 ----
    // xh = x @ pre_w1 + pre_b1                       -> buf0
    gemm_fused<<<nb_g, 256, 0, stream>>>(x, pre_w1, F_IN, nullptr, nullptr, 0,
                                         pre_b1, nullptr, buf0, N, 0);
    // tx1 -> buf1, sage-mean -> buf2
    aggregate_kernel<<<nb_w, 256, 0, stream>>>(buf0, offs, slot_src, slot_nrm,
                                               slot_we, loop_w, cnt, buf1, buf2, N);
    // o1 = xh@cw0 + tx1@cw1 + cb                     -> buf3
    gemm_fused<<<nb_g, 256, 0, stream>>>(buf0, cheb_w01, H, buf1, cheb_w11, H,
                                         cheb_b1, nullptr, buf3, N, 0);
    // t = leaky(o1) + leaky(sagg@sw + sb)            -> buf1
    gemm_fused<<<nb_g, 256, 0, stream>>>(buf2, sage_w1, H, nullptr, nullptr, 0,
                                         sage_b1, buf3, buf1, N, 1);
    // x1 = t @ lw + lb                               -> buf2
    gemm_fused<<<nb_g, 256, 0, stream>>>(buf1, lin_w1, H, nullptr, nullptr, 0,
                                         lin_b1, nullptr, buf2, N, 0);

    // ---- cell 2 (input = buf2) ----
    gemm_fused<<<nb_g, 256, 0, stream>>>(buf2, pre_w2, H, nullptr, nullptr, 0,
                                         pre_b2, nullptr, buf0, N, 0);
    aggregate_kernel<<<nb_w, 256, 0, stream>>>(buf0, offs, slot_src, slot_nrm,
                                               slot_we, loop_w, cnt, buf1, buf3, N);
    gemm_fused<<<nb_g, 256, 0, stream>>>(buf0, cheb_w02, H, buf1, cheb_w12, H,
                                         cheb_b2, nullptr, buf2, N, 0);
    gemm_fused<<<nb_g, 256, 0, stream>>>(buf3, sage_w2, H, nullptr, nullptr, 0,
                                         sage_b2, buf2, buf1, N, 1);
    gemm_fused<<<nb_g, 256, 0, stream>>>(buf1, lin_w2, H, nullptr, nullptr, 0,
                                         lin_b2, nullptr, buf3, N, 0);

    // classifier + log_softmax -> d_out
    cls_kernel<<<nb_w, 256, 0, stream>>>(buf3, cls_w, cls_b, (float*)d_out, N, C);
}